// Round 7
// baseline (267.784 us; speedup 1.0000x reference)
//
#include <hip/hip_runtime.h>

#define L 4096
#define D 512
#define NCH 16   // context n-chunks (256 n per chunk)

typedef __bf16 bf16x8 __attribute__((ext_vector_type(8)));
typedef float  f32x4  __attribute__((ext_vector_type(4)));

__device__ __forceinline__ void load_lds16(const void* g, void* l) {
    __builtin_amdgcn_global_load_lds(
        (const __attribute__((address_space(1))) void*)g,
        (__attribute__((address_space(3))) void*)l, 16, 0, 0);
}

__device__ __forceinline__ void barrier_mem() {
    asm volatile("" ::: "memory");
    __builtin_amdgcn_s_barrier();
    asm volatile("" ::: "memory");
}

// ---------------------------------------------------------------------------
// merged f32 -> bf16 conversion for x, Wqkv, Wout (contiguous dst regions)
// ---------------------------------------------------------------------------
#define NX8  (8 * 4096 * 512 / 8)
#define NW18 (1536 * 512 / 8)
#define NW28 (512 * 512 / 8)
__global__ __launch_bounds__(256) void convert_all(const float* __restrict__ x,
                                                   const float* __restrict__ Wq,
                                                   const float* __restrict__ Wo,
                                                   __bf16* __restrict__ dst) {
    int i = blockIdx.x * 256 + threadIdx.x;
    if (i >= NX8 + NW18 + NW28) return;
    const float* s;
    if (i < NX8)             s = x  + (size_t)i * 8;
    else if (i < NX8 + NW18) s = Wq + (size_t)(i - NX8) * 8;
    else                     s = Wo + (size_t)(i - NX8 - NW18) * 8;
    float4 a = ((const float4*)s)[0], b = ((const float4*)s)[1];
    bf16x8 o = {(__bf16)a.x, (__bf16)a.y, (__bf16)a.z, (__bf16)a.w,
                (__bf16)b.x, (__bf16)b.y, (__bf16)b.z, (__bf16)b.w};
    *(bf16x8*)(dst + (size_t)i * 8) = o;
}

// ---------------------------------------------------------------------------
// 256x128-tile TN bf16 MFMA GEMM, 3-slot K-half ring, 2 blocks/CU.
// C[b][m][n] = sum_k A[b][m][k]*B[b][n][k] (+bias[n]). 256 thr = 4 waves 2Mx2N;
// each wave owns a 128x64 output sub-tile. LDS 72 KB -> TWO blocks per CU
// (the R6 post-mortem: 128KB/1-block lockstep left LDS-latency exposed with
// nothing to overlap; cross-block TLP hides it per m114).
// K-half q (32 k): A-unit 256x32 (16KB, 4 loads/thr), B-unit 128x32 (8KB, 2).
// Body q: {vmcnt(6) [retire pair q; 12 outstanding]; barrier [all waves'
//   pair-q loads landed]; stage pair q+2 -> slot (q+2)%3; 12x ds_read_b128
//   slot q%3; lgkm(0)+sched_barrier; setprio(1) 32 MFMA setprio(0)}.
// WAR: slot (q+2)%3 was last read at body q-1 ((q-1)%3 == (q+2)%3); those
//   reads drain at body q-1's lgkm(0) before its MFMA, hence before every
//   wave reaches body q's barrier; stage is issued post-barrier. No race.
// vmcnt ladder: prologue 12 out; steady vmcnt(6); last body vmcnt(0).
// Swizzle (64B rows): slot (row,cc) holds k-chunk cc^((row>>1)&3); read
//   chunk g^((row>>1)&3) -> 2-way bank aliasing max (free per m136).
// ---------------------------------------------------------------------------
template <int M, int N, int K, typename CT>
__global__ __launch_bounds__(256, 2) void gemm_bf16_256x128(
    const __bf16* __restrict__ A, size_t aStride,
    const __bf16* __restrict__ B, size_t bStride,
    CT* __restrict__ C, size_t cStride,
    const float* __restrict__ bias) {
    __shared__ __align__(16) __bf16 sA[3][256 * 32];   // 48 KB
    __shared__ __align__(16) __bf16 sB[3][128 * 32];   // 24 KB
    constexpr int NQ = K / 32;
    const int b  = blockIdx.z;
    const int m0 = blockIdx.y * 256;
    const int n0 = blockIdx.x * 128;
    const int t    = threadIdx.x;
    const int wave = t >> 6, lane = t & 63;
    const int wm = (wave >> 1) * 128;   // wave M-offset (2 halves)
    const int wn = (wave & 1) * 64;     // wave N-offset (2 halves)
    const int fr = lane & 15, g = lane >> 4;
    const __bf16* Ab = A + (size_t)b * aStride + (size_t)m0 * K;
    const __bf16* Bb = B + (size_t)b * bStride + (size_t)n0 * K;
    CT* Cb = C + (size_t)b * cStride;

    f32x4 acc[8][4];
#pragma unroll
    for (int i = 0; i < 8; i++)
#pragma unroll
        for (int j = 0; j < 4; j++) acc[i][j] = (f32x4)(0.0f);

    auto stageA = [&](int q, __bf16* slot) {
#pragma unroll
        for (int it = 0; it < 4; ++it) {
            const int gi = it * 256 + t;          // 16B granule 0..1023
            const int row = gi >> 2, cc = gi & 3;
            const int scc = cc ^ ((row >> 1) & 3);
            load_lds16(Ab + (size_t)row * K + q * 32 + scc * 8, slot + gi * 8);
        }
    };
    auto stageB = [&](int q, __bf16* slot) {
#pragma unroll
        for (int it = 0; it < 2; ++it) {
            const int gi = it * 256 + t;          // 16B granule 0..511
            const int row = gi >> 2, cc = gi & 3;
            const int scc = cc ^ ((row >> 1) & 3);
            load_lds16(Bb + (size_t)row * K + q * 32 + scc * 8, slot + gi * 8);
        }
    };
    auto rdFrag = [&](const __bf16* slot, int rowbase) -> bf16x8 {
        const int row = rowbase + fr;
        return *(const bf16x8*)&slot[row * 32 + ((g ^ ((row >> 1) & 3)) * 8)];
    };

    // prologue: pairs 0,1 (12 loads outstanding)
    stageB(0, sB[0]); stageA(0, sA[0]);
    stageB(1, sB[1]); stageA(1, sA[1]);

    for (int q = 0; q < NQ; ++q) {
        const int sl = q % 3;
        if (q < NQ - 1) asm volatile("s_waitcnt vmcnt(6)" ::: "memory");
        else            asm volatile("s_waitcnt vmcnt(0)" ::: "memory");
        barrier_mem();                          // pair q landed (all waves)
        if (q + 2 < NQ) {
            const int ss = (q + 2) % 3;
            stageB(q + 2, sB[ss]);
            stageA(q + 2, sA[ss]);
        }
        bf16x8 fB[4], fA[8];
#pragma unroll
        for (int j = 0; j < 4; ++j) fB[j] = rdFrag(sB[sl], wn + j * 16);
#pragma unroll
        for (int i = 0; i < 8; ++i) fA[i] = rdFrag(sA[sl], wm + i * 16);
        asm volatile("s_waitcnt lgkmcnt(0)" ::: "memory");
        __builtin_amdgcn_sched_barrier(0);
        __builtin_amdgcn_s_setprio(1);
#pragma unroll
        for (int i = 0; i < 8; ++i)
#pragma unroll
            for (int j = 0; j < 4; ++j)
                acc[i][j] = __builtin_amdgcn_mfma_f32_16x16x32_bf16(
                    fA[i], fB[j], acc[i][j], 0, 0, 0);
        __builtin_amdgcn_s_setprio(0);
    }

    // epilogue: j-innermost so adjacent 32B chunks issue back-to-back
    const int rb = g * 4;
    float bv[4];
#pragma unroll
    for (int j = 0; j < 4; ++j) bv[j] = bias ? bias[n0 + wn + j * 16 + fr] : 0.0f;
#pragma unroll
    for (int i = 0; i < 8; ++i) {
#pragma unroll
        for (int r = 0; r < 4; ++r) {
            const int m = m0 + wm + i * 16 + rb + r;
            CT* rowp = Cb + (size_t)m * N + n0 + wn + fr;
#pragma unroll
            for (int j = 0; j < 4; ++j)
                rowp[j * 16] = (CT)(acc[i][j][r] + bv[j]);
        }
    }
}

// ---------------------------------------------------------------------------
// k-row stats over bf16 k rows: per row compute (max, 1/sumexp). grid 4096.
// ---------------------------------------------------------------------------
__global__ __launch_bounds__(256) void kstats(const __bf16* __restrict__ qkv,
                                              float2* __restrict__ stats) {
    const int r = blockIdx.x;
    const int b = r >> 9, hc = r & 511;
    const __bf16* row = qkv + (size_t)b * 1536 * L + (size_t)(512 + hc) * L;
    __shared__ float sred[4];
    const int t = threadIdx.x;
    const bf16x8* p = (const bf16x8*)row;
    bf16x8 c0 = p[t * 2], c1 = p[t * 2 + 1];
    float v[16];
    float m = -1e30f;
#pragma unroll
    for (int j = 0; j < 8; j++) {
        v[j] = (float)c0[j];
        v[8 + j] = (float)c1[j];
    }
#pragma unroll
    for (int j = 0; j < 16; j++) m = fmaxf(m, v[j]);
#pragma unroll
    for (int off = 32; off > 0; off >>= 1) m = fmaxf(m, __shfl_down(m, off, 64));
    if ((t & 63) == 0) sred[t >> 6] = m;
    __syncthreads();
    const float m4 = fmaxf(fmaxf(sred[0], sred[1]), fmaxf(sred[2], sred[3]));
    float s = 0.f;
#pragma unroll
    for (int j = 0; j < 16; j++) s += __expf(v[j] - m4);
#pragma unroll
    for (int off = 32; off > 0; off >>= 1) s += __shfl_down(s, off, 64);
    __syncthreads();
    if ((t & 63) == 0) sred[t >> 6] = s;
    __syncthreads();
    if (t == 0) {
        const float stot = sred[0] + sred[1] + sred[2] + sred[3];
        stats[r] = make_float2(m4, 1.0f / stot);
    }
}

// ---------------------------------------------------------------------------
// MFMA context partials: ctxp[chunk][bh][d][e] (f32, d-major) =
//   sum_{n in chunk} exp(k[d,n]-m_d) * v[e,n]   (un-normalized; 1/s at reduce)
// grid (NCH, 64 bh), block 256. Each of 4 waves takes a 64-n K-slice.
// ---------------------------------------------------------------------------
#define SKS 264   // LDS bf16 row stride (256 data + 8 pad)
__global__ __launch_bounds__(256) void context_mfma(const __bf16* __restrict__ qkv,
                                                    const float2* __restrict__ stats,
                                                    float* __restrict__ ctxp) {
    __shared__ __align__(16) __bf16 smem[2 * 64 * SKS];  // 67.6 KB; reused as f32 red[4][4096]
    __shared__ float smax[64];
    __bf16* sk = smem;
    __bf16* sv = smem + 64 * SKS;
    const int chunk = blockIdx.x;
    const int bh = blockIdx.y;
    const int b = bh >> 3, h = bh & 7;
    const __bf16* kbase = qkv + (size_t)b * 1536 * L + (size_t)(512 + h * 64) * L;
    const __bf16* vbase = qkv + (size_t)b * 1536 * L + (size_t)(1024 + h * 64) * L;
    const int t = threadIdx.x;
    if (t < 64) smax[t] = stats[bh * 64 + t].x;
    __syncthreads();

    // stage: thread t -> row d = t>>2, n-quarter (t&3)*64
    {
        const int d = t >> 2, noff = (t & 3) * 64;
        const int n0 = chunk * 256;
        const __bf16* kp = kbase + (size_t)d * L + n0 + noff;
        const __bf16* vp = vbase + (size_t)d * L + n0 + noff;
        const float md = smax[d];
#pragma unroll
        for (int c = 0; c < 8; c++) {
            bf16x8 kk = *(const bf16x8*)(kp + c * 8);
            bf16x8 vv = *(const bf16x8*)(vp + c * 8);
            bf16x8 ek;
#pragma unroll
            for (int j = 0; j < 8; j++) ek[j] = (__bf16)__expf((float)kk[j] - md);
            *(bf16x8*)&sk[d * SKS + noff + c * 8] = ek;
            *(bf16x8*)&sv[d * SKS + noff + c * 8] = vv;
        }
    }
    __syncthreads();

    // MFMA: wave w covers n in [w*64, w*64+64)
    const int wave = t >> 6, lane = t & 63;
    const int fr = lane & 15, kq = (lane >> 4) * 8;
    f32x4 acc[4][4];
#pragma unroll
    for (int i = 0; i < 4; i++)
#pragma unroll
        for (int j = 0; j < 4; j++) acc[i][j] = (f32x4)(0.0f);
#pragma unroll
    for (int kh = 0; kh < 2; kh++) {
        const int koff = wave * 64 + kh * 32 + kq;
        bf16x8 af[4], bfr[4];
#pragma unroll
        for (int i = 0; i < 4; i++) {
            af[i]  = *(const bf16x8*)&sk[(i * 16 + fr) * SKS + koff];
            bfr[i] = *(const bf16x8*)&sv[(i * 16 + fr) * SKS + koff];
        }
#pragma unroll
        for (int i = 0; i < 4; i++)
#pragma unroll
            for (int j = 0; j < 4; j++)
                acc[i][j] = __builtin_amdgcn_mfma_f32_16x16x32_bf16(af[i], bfr[j], acc[i][j], 0, 0, 0);
    }
    __syncthreads();   // MFMA LDS reads done; safe to overwrite smem

    // cross-wave reduce via LDS: red[w][d*64+e] (d = A rows, e = B rows)
    float* red = (float*)smem;   // 4 * 4096 f32 = 64 KB
    const int col = lane & 15, rbase = (lane >> 4) * 4;
#pragma unroll
    for (int i = 0; i < 4; i++)
#pragma unroll
        for (int j = 0; j < 4; j++)
#pragma unroll
            for (int r = 0; r < 4; r++) {
                const int dd = i * 16 + rbase + r;
                const int ee = j * 16 + col;
                red[wave * 4096 + dd * 64 + ee] = acc[i][j][r];
            }
    __syncthreads();
    float* cp = ctxp + ((size_t)chunk * 64 + bh) * 4096;
#pragma unroll
    for (int gg = 0; gg < 4; gg++) {
        const int idx = t * 16 + gg * 4;
        f32x4 s = *(const f32x4*)&red[idx];
        s += *(const f32x4*)&red[4096 + idx];
        s += *(const f32x4*)&red[8192 + idx];
        s += *(const f32x4*)&red[12288 + idx];
        *(f32x4*)&cp[idx] = s;
    }
}

// ---------------------------------------------------------------------------
// reduce ctx partials over chunks, apply 1/s_d, transpose [d][e]->[e][d],
// emit bf16 ctxT[bh][e][d]. grid 256.
// ---------------------------------------------------------------------------
__global__ __launch_bounds__(256) void ctx_reduce(const float* __restrict__ ctxp,
                                                  const float2* __restrict__ stats,
                                                  __bf16* __restrict__ ctxT) {
    const int bh = blockIdx.x >> 2, quarter = blockIdx.x & 3;
    const int t = threadIdx.x;
    const int flat = quarter * 1024 + t * 4;   // d-major: d = flat>>6, e0 = flat&63
    const int d = flat >> 6, e0 = flat & 63;
    f32x4 s = (f32x4)(0.0f);
    for (int ch = 0; ch < NCH; ch++)
        s += *(const f32x4*)&ctxp[((size_t)ch * 64 + bh) * 4096 + flat];
    const float inv = stats[bh * 64 + d].y;
    __bf16* o = ctxT + (size_t)bh * 4096;
#pragma unroll
    for (int j = 0; j < 4; j++) o[(e0 + j) * 64 + d] = (__bf16)(s[j] * inv);
}

// ---------------------------------------------------------------------------
// pv_fused: per (bh, 256-col tile): q-softmax (unnormalized exp in LDS bf16)
// + MFMA 256x64 K=64 against ctxT, normalize in epilogue, write bf16 outT.
// ---------------------------------------------------------------------------
#define SPS 66   // LDS row stride (bf16)
__global__ __launch_bounds__(256) void pv_fused(__bf16* __restrict__ qkv,
                                                const __bf16* __restrict__ ctxT) {
    __shared__ __align__(16) __bf16 sp[256 * SPS];   // p rows [n][d]
    __shared__ __align__(16) __bf16 sctx[64 * SPS];  // ctxT rows [e][d]
    __shared__ float sinv[256];
    const int tileN = blockIdx.x;
    const int bh = blockIdx.y;
    const int b = bh >> 3, h = bh & 7;
    const int t = threadIdx.x;
    const int n0 = tileN * 256;
    const __bf16* qbase = qkv + (size_t)b * 1536 * L + (size_t)(h * 64) * L;

    {   // stage ctxT (64x64 bf16)
        const int e = t >> 2, c = t & 3;
        const bf16x8* src = (const bf16x8*)(ctxT + ((size_t)bh * 64 + e) * 64 + c * 16);
        *(bf16x8*)&sctx[e * SPS + c * 16] = src[0];
        *(bf16x8*)&sctx[e * SPS + c * 16 + 8] = src[1];
    }

    // read bf16 q column (coalesced across lanes), exp, sum, stage
    float m = -1e30f;
    float qv[64];
#pragma unroll
    for (int d = 0; d < 64; d++) {
        qv[d] = (float)qbase[(size_t)d * L + n0 + t];
        m = fmaxf(m, qv[d]);
    }
    float s = 0.f;
#pragma unroll
    for (int d0 = 0; d0 < 64; d0 += 8) {
        bf16x8 ek;
#pragma unroll
        for (int j = 0; j < 8; j++) {
            float e = __expf(qv[d0 + j] - m);
            s += e;
            ek[j] = (__bf16)e;
        }
        *(bf16x8*)&sp[t * SPS + d0] = ek;
    }
    sinv[t] = 1.0f / s;
    __syncthreads();

    // MFMA: out[n][e] = sum_d p[n][d] * ctxT[e][d]; 4 waves x 64 rows
    const int wave = t >> 6, lane = t & 63;
    const int wm = wave * 64;
    const int fr = lane & 15, kq = (lane >> 4) * 8;
    f32x4 acc[4][4];
#pragma unroll
    for (int i = 0; i < 4; i++)
#pragma unroll
        for (int j = 0; j < 4; j++) acc[i][j] = (f32x4)(0.0f);
#pragma unroll
    for (int kh = 0; kh < 2; kh++) {
        bf16x8 af[4], bfr[4];
#pragma unroll
        for (int i = 0; i < 4; i++)
            af[i] = *(const bf16x8*)&sp[(wm + i * 16 + fr) * SPS + kh * 32 + kq];
#pragma unroll
        for (int j = 0; j < 4; j++)
            bfr[j] = *(const bf16x8*)&sctx[(j * 16 + fr) * SPS + kh * 32 + kq];
#pragma unroll
        for (int i = 0; i < 4; i++)
#pragma unroll
            for (int j = 0; j < 4; j++)
                acc[i][j] = __builtin_amdgcn_mfma_f32_16x16x32_bf16(af[i], bfr[j], acc[i][j], 0, 0, 0);
    }

    // epilogue: normalize by 1/s[n], write bf16 outT[b][n][h*64+e]
    __bf16* ob = qkv + (size_t)b * 1536 * L + (size_t)512 * L;
    const int col = lane & 15, rbase = (lane >> 4) * 4;
#pragma unroll
    for (int i = 0; i < 4; i++) {
#pragma unroll
        for (int r = 0; r < 4; r++) {
            const int nl = wm + i * 16 + rbase + r;
            const float inv = sinv[nl];
            const size_t rowoff = (size_t)(n0 + nl) * 512 + h * 64;
#pragma unroll
            for (int j = 0; j < 4; j++)
                ob[rowoff + j * 16 + col] = (__bf16)(acc[i][j][r] * inv);
        }
    }
}

// ---------------------------------------------------------------------------
extern "C" void kernel_launch(void* const* d_in, const int* in_sizes, int n_in,
                              void* d_out, int out_size, void* d_ws, size_t ws_size,
                              hipStream_t stream) {
    const float* x    = (const float*)d_in[0];
    const float* Wqkv = (const float*)d_in[1];
    const float* Wout = (const float*)d_in[2];
    const float* bout = (const float*)d_in[3];
    float* y = (float*)d_out;

    __bf16* qkv   = (__bf16*)d_ws;                               // 8*1536*4096 bf16
    float*  ctxp  = (float*)(qkv + (size_t)8 * 1536 * L);        // NCH*64*4096 f32
    __bf16* xb    = (__bf16*)(ctxp + (size_t)NCH * 64 * 4096);   // 8*4096*512 bf16
    __bf16* Wqb   = xb + (size_t)8 * 4096 * 512;                 // 1536*512 bf16
    __bf16* Wob   = Wqb + (size_t)1536 * 512;                    // 512*512 bf16
    float2* stats = (float2*)(Wob + (size_t)512 * 512);          // 4096 float2
    __bf16* ctxT  = (__bf16*)(stats + 4096);                     // 64*4096 bf16

    const int convBlocks = (NX8 + NW18 + NW28 + 255) / 256;
    convert_all<<<dim3(convBlocks), 256, 0, stream>>>(x, Wqkv, Wout, xb);

    // qkv[b][o][l] = sum_d Wqkv[o][d] * x[b][l][d]   (M=1536, N=4096, K=512), bf16 out
    gemm_bf16_256x128<1536, 4096, 512, __bf16><<<dim3(4096 / 128, 1536 / 256, 8), 256, 0, stream>>>(
        Wqb, 0, xb, (size_t)4096 * 512, qkv, (size_t)1536 * 4096, nullptr);

    kstats<<<dim3(4096), 256, 0, stream>>>(qkv, stats);
    context_mfma<<<dim3(NCH, 64), 256, 0, stream>>>(qkv, stats, ctxp);
    ctx_reduce<<<dim3(256), 256, 0, stream>>>(ctxp, stats, ctxT);
    pv_fused<<<dim3(L / 256, 64), 256, 0, stream>>>(qkv, ctxT);

    // y[b][l][d] = sum_c outT[b][l][c] * Wout[d][c] + bout[d]  (M=4096, N=512, K=512), f32 out
    const __bf16* outT = qkv + (size_t)512 * L;
    gemm_bf16_256x128<4096, 512, 512, float><<<dim3(512 / 128, 4096 / 256, 8), 256, 0, stream>>>(
        outT, (size_t)1536 * L, Wob, 0, y, (size_t)4096 * 512, bout);
}

// Round 9
// 266.765 us; speedup vs baseline: 1.0038x; 1.0038x over previous
//
#include <hip/hip_runtime.h>

#define L 4096
#define D 512
#define NCH 16   // context n-chunks (256 n per chunk)

typedef __bf16 bf16x8 __attribute__((ext_vector_type(8)));
typedef float  f32x4  __attribute__((ext_vector_type(4)));

__device__ __forceinline__ void load_lds16(const void* g, void* l) {
    __builtin_amdgcn_global_load_lds(
        (const __attribute__((address_space(1))) void*)g,
        (__attribute__((address_space(3))) void*)l, 16, 0, 0);
}

__device__ __forceinline__ void barrier_mem() {
    asm volatile("" ::: "memory");
    __builtin_amdgcn_s_barrier();
    asm volatile("" ::: "memory");
}

// ---------------------------------------------------------------------------
// merged f32 -> bf16 conversion for x, Wqkv, Wout (contiguous dst regions)
// ---------------------------------------------------------------------------
#define NX8  (8 * 4096 * 512 / 8)
#define NW18 (1536 * 512 / 8)
#define NW28 (512 * 512 / 8)
__global__ __launch_bounds__(256) void convert_all(const float* __restrict__ x,
                                                   const float* __restrict__ Wq,
                                                   const float* __restrict__ Wo,
                                                   __bf16* __restrict__ dst) {
    int i = blockIdx.x * 256 + threadIdx.x;
    if (i >= NX8 + NW18 + NW28) return;
    const float* s;
    if (i < NX8)             s = x  + (size_t)i * 8;
    else if (i < NX8 + NW18) s = Wq + (size_t)(i - NX8) * 8;
    else                     s = Wo + (size_t)(i - NX8 - NW18) * 8;
    float4 a = ((const float4*)s)[0], b = ((const float4*)s)[1];
    bf16x8 o = {(__bf16)a.x, (__bf16)a.y, (__bf16)a.z, (__bf16)a.w,
                (__bf16)b.x, (__bf16)b.y, (__bf16)b.z, (__bf16)b.w};
    *(bf16x8*)(dst + (size_t)i * 8) = o;
}

// ---------------------------------------------------------------------------
// 256x128-tile TN bf16 MFMA GEMM, 3-slot ring, 2 blocks/CU, in-wave pipeline.
// 256 thr = 4 waves 2Mx2N; per-wave 128x64 output. LDS 72 KB (sB first: 24KB,
// sA 48KB -> all ds_read offsets < 64KB imm).
// K-loop FULLY UNROLLED (NQ=16): slots, ds offsets, global offsets all become
// compile-time -> per-body address VALU ~0 (R7 post-mortem: VALU ~540cyc/body
// was a first-class serial term).
// Body q: {vmcnt(0) [pair q+1 landed; staged 1 body ago]; barrier;
//   stage pair q+2 -> slot (q+2)%3; read B-q (4 ds_read, slot q%3);
//   read A-(q+1) -> ping/pong (8 ds_read, slot (q+1)%3); lgkmcnt(8)
//   [drains B-q + A-q, leaves A-(q+1) retiring UNDER the MFMA burst];
//   sched_barrier; setprio(1) 32 MFMA (A-q x B-q) setprio(0)}.
// Hazard proofs:
//  RAW: pair q+1 staged at body q-1 post-barrier; my vmcnt(0)@q drains it,
//   barrier@q extends to all waves.
//  WAR(stage slot (q+2)%3 == (q-1)%3): B-(q-1) reads drained at body q-1's
//   lgkmcnt(8); A-(q-1) reads (issued body q-2) likewise; both precede each
//   wave's barrier@q; stage is post-barrier.
//  lgkm in-order retirement (LDS) makes lgkmcnt(8) drain exactly {A-q, B-q}.
// Swizzle: slot (row,cc) holds k-chunk cc^((row>>1)&3); read chunk
//   g^((fr>>1)&3) (rowbase ≡ 0 mod 16 -> lane-const) -> 2-way aliasing, free.
// ---------------------------------------------------------------------------
template <int M, int N, int K, typename CT>
__global__ __launch_bounds__(256, 2) void gemm_bf16_pipe(
    const __bf16* __restrict__ A, size_t aStride,
    const __bf16* __restrict__ B, size_t bStride,
    CT* __restrict__ C, size_t cStride,
    const float* __restrict__ bias) {
    __shared__ __align__(16) __bf16 sB[3][128 * 32];   // 24 KB (low offsets)
    __shared__ __align__(16) __bf16 sA[3][256 * 32];   // 48 KB
    constexpr int NQ = K / 32;                         // 16
    const int b  = blockIdx.z;
    const int m0 = blockIdx.y * 256;
    const int n0 = blockIdx.x * 128;
    const int t    = threadIdx.x;
    const int wave = t >> 6, lane = t & 63;
    const int wm = (wave >> 1) * 128;
    const int wn = (wave & 1) * 64;
    const int fr = lane & 15, g = lane >> 4;
    const __bf16* Ab = A + (size_t)b * aStride + (size_t)m0 * K;
    const __bf16* Bb = B + (size_t)b * bStride + (size_t)n0 * K;
    CT* Cb = C + (size_t)b * cStride;

    // per-thread global source pointers (swizzled-chunk source, computed once)
    const __bf16* pA_[4];
    const __bf16* pB_[2];
#pragma unroll
    for (int it = 0; it < 4; ++it) {
        const int gi = it * 256 + t, row = gi >> 2, cc = gi & 3;
        pA_[it] = Ab + (size_t)row * K + (cc ^ ((row >> 1) & 3)) * 8;
    }
#pragma unroll
    for (int it = 0; it < 2; ++it) {
        const int gi = it * 256 + t, row = gi >> 2, cc = gi & 3;
        pB_[it] = Bb + (size_t)row * K + (cc ^ ((row >> 1) & 3)) * 8;
    }
    // per-lane LDS read bases (elements); swizzle chunk is lane-constant
    const int lchunk = (g ^ ((fr >> 1) & 3)) * 8;
    const int laneA = (wm + fr) * 32 + lchunk;
    const int laneB = (wn + fr) * 32 + lchunk;

    f32x4 acc[8][4];
#pragma unroll
    for (int i = 0; i < 8; i++)
#pragma unroll
        for (int j = 0; j < 4; j++) acc[i][j] = (f32x4)(0.0f);

    auto stagePair = [&](int q, int sl) {
#pragma unroll
        for (int it = 0; it < 4; ++it)
            load_lds16(pA_[it] + q * 32, &sA[sl][(it * 256 + t) * 8]);
#pragma unroll
        for (int it = 0; it < 2; ++it)
            load_lds16(pB_[it] + q * 32, &sB[sl][(it * 256 + t) * 8]);
    };

    bf16x8 fA0[8], fA1[8], fB[4];

    // prologue: stage pairs 0,1; wait pair 0; read A-0 fragments
    stagePair(0, 0);
    stagePair(1, 1);
    asm volatile("s_waitcnt vmcnt(6)" ::: "memory");
    barrier_mem();
#pragma unroll
    for (int i = 0; i < 8; ++i)
        fA0[i] = *(const bf16x8*)&sA[0][laneA + i * 512];

#pragma unroll
    for (int q = 0; q < NQ; ++q) {
        asm volatile("s_waitcnt vmcnt(0)" ::: "memory");
        barrier_mem();                              // pair q+1 visible; slots safe
        if (q + 2 < NQ) stagePair(q + 2, (q + 2) % 3);
        // B fragments for pair q (slot valid since body q-1)
#pragma unroll
        for (int j = 0; j < 4; ++j)
            fB[j] = *(const bf16x8*)&sB[q % 3][laneB + j * 512];
        bf16x8* fAc = (q & 1) ? fA1 : fA0;
        bf16x8* fAn = (q & 1) ? fA0 : fA1;
        if (q + 1 < NQ) {
#pragma unroll
            for (int i = 0; i < 8; ++i)
                fAn[i] = *(const bf16x8*)&sA[(q + 1) % 3][laneA + i * 512];
            asm volatile("s_waitcnt lgkmcnt(8)" ::: "memory");  // B-q + A-q done
        } else {
            asm volatile("s_waitcnt lgkmcnt(0)" ::: "memory");
        }
        __builtin_amdgcn_sched_barrier(0);
        __builtin_amdgcn_s_setprio(1);
#pragma unroll
        for (int i = 0; i < 8; ++i)
#pragma unroll
            for (int j = 0; j < 4; ++j)
                acc[i][j] = __builtin_amdgcn_mfma_f32_16x16x32_bf16(
                    fAc[i], fB[j], acc[i][j], 0, 0, 0);
        __builtin_amdgcn_s_setprio(0);
    }

    // epilogue: j-innermost so adjacent 32B chunks issue back-to-back
    const int rb = g * 4;
    float bv[4];
#pragma unroll
    for (int j = 0; j < 4; ++j) bv[j] = bias ? bias[n0 + wn + j * 16 + fr] : 0.0f;
#pragma unroll
    for (int i = 0; i < 8; ++i) {
#pragma unroll
        for (int r = 0; r < 4; ++r) {
            const int m = m0 + wm + i * 16 + rb + r;
            CT* rowp = Cb + (size_t)m * N + n0 + wn + fr;
#pragma unroll
            for (int j = 0; j < 4; ++j)
                rowp[j * 16] = (CT)(acc[i][j][r] + bv[j]);
        }
    }
}

// ---------------------------------------------------------------------------
// k-row stats over bf16 k rows: per row compute (max, 1/sumexp). grid 4096.
// ---------------------------------------------------------------------------
__global__ __launch_bounds__(256) void kstats(const __bf16* __restrict__ qkv,
                                              float2* __restrict__ stats) {
    const int r = blockIdx.x;
    const int b = r >> 9, hc = r & 511;
    const __bf16* row = qkv + (size_t)b * 1536 * L + (size_t)(512 + hc) * L;
    __shared__ float sred[4];
    const int t = threadIdx.x;
    const bf16x8* p = (const bf16x8*)row;
    bf16x8 c0 = p[t * 2], c1 = p[t * 2 + 1];
    float v[16];
    float m = -1e30f;
#pragma unroll
    for (int j = 0; j < 8; j++) {
        v[j] = (float)c0[j];
        v[8 + j] = (float)c1[j];
    }
#pragma unroll
    for (int j = 0; j < 16; j++) m = fmaxf(m, v[j]);
#pragma unroll
    for (int off = 32; off > 0; off >>= 1) m = fmaxf(m, __shfl_down(m, off, 64));
    if ((t & 63) == 0) sred[t >> 6] = m;
    __syncthreads();
    const float m4 = fmaxf(fmaxf(sred[0], sred[1]), fmaxf(sred[2], sred[3]));
    float s = 0.f;
#pragma unroll
    for (int j = 0; j < 16; j++) s += __expf(v[j] - m4);
#pragma unroll
    for (int off = 32; off > 0; off >>= 1) s += __shfl_down(s, off, 64);
    __syncthreads();
    if ((t & 63) == 0) sred[t >> 6] = s;
    __syncthreads();
    if (t == 0) {
        const float stot = sred[0] + sred[1] + sred[2] + sred[3];
        stats[r] = make_float2(m4, 1.0f / stot);
    }
}

// ---------------------------------------------------------------------------
// MFMA context partials: ctxp[chunk][bh][d][e] (f32, d-major) =
//   sum_{n in chunk} exp(k[d,n]-m_d) * v[e,n]   (un-normalized; 1/s at reduce)
// grid (NCH, 64 bh), block 256. Each of 4 waves takes a 64-n K-slice.
// ---------------------------------------------------------------------------
#define SKS 264   // LDS bf16 row stride (256 data + 8 pad)
__global__ __launch_bounds__(256) void context_mfma(const __bf16* __restrict__ qkv,
                                                    const float2* __restrict__ stats,
                                                    float* __restrict__ ctxp) {
    __shared__ __align__(16) __bf16 smem[2 * 64 * SKS];  // 67.6 KB; reused as f32 red[4][4096]
    __shared__ float smax[64];
    __bf16* sk = smem;
    __bf16* sv = smem + 64 * SKS;
    const int chunk = blockIdx.x;
    const int bh = blockIdx.y;
    const int b = bh >> 3, h = bh & 7;
    const __bf16* kbase = qkv + (size_t)b * 1536 * L + (size_t)(512 + h * 64) * L;
    const __bf16* vbase = qkv + (size_t)b * 1536 * L + (size_t)(1024 + h * 64) * L;
    const int t = threadIdx.x;
    if (t < 64) smax[t] = stats[bh * 64 + t].x;
    __syncthreads();

    // stage: thread t -> row d = t>>2, n-quarter (t&3)*64
    {
        const int d = t >> 2, noff = (t & 3) * 64;
        const int n0 = chunk * 256;
        const __bf16* kp = kbase + (size_t)d * L + n0 + noff;
        const __bf16* vp = vbase + (size_t)d * L + n0 + noff;
        const float md = smax[d];
#pragma unroll
        for (int c = 0; c < 8; c++) {
            bf16x8 kk = *(const bf16x8*)(kp + c * 8);
            bf16x8 vv = *(const bf16x8*)(vp + c * 8);
            bf16x8 ek;
#pragma unroll
            for (int j = 0; j < 8; j++) ek[j] = (__bf16)__expf((float)kk[j] - md);
            *(bf16x8*)&sk[d * SKS + noff + c * 8] = ek;
            *(bf16x8*)&sv[d * SKS + noff + c * 8] = vv;
        }
    }
    __syncthreads();

    // MFMA: wave w covers n in [w*64, w*64+64)
    const int wave = t >> 6, lane = t & 63;
    const int fr = lane & 15, kq = (lane >> 4) * 8;
    f32x4 acc[4][4];
#pragma unroll
    for (int i = 0; i < 4; i++)
#pragma unroll
        for (int j = 0; j < 4; j++) acc[i][j] = (f32x4)(0.0f);
#pragma unroll
    for (int kh = 0; kh < 2; kh++) {
        const int koff = wave * 64 + kh * 32 + kq;
        bf16x8 af[4], bfr[4];
#pragma unroll
        for (int i = 0; i < 4; i++) {
            af[i]  = *(const bf16x8*)&sk[(i * 16 + fr) * SKS + koff];
            bfr[i] = *(const bf16x8*)&sv[(i * 16 + fr) * SKS + koff];
        }
#pragma unroll
        for (int i = 0; i < 4; i++)
#pragma unroll
            for (int j = 0; j < 4; j++)
                acc[i][j] = __builtin_amdgcn_mfma_f32_16x16x32_bf16(af[i], bfr[j], acc[i][j], 0, 0, 0);
    }
    __syncthreads();   // MFMA LDS reads done; safe to overwrite smem

    // cross-wave reduce via LDS: red[w][d*64+e] (d = A rows, e = B rows)
    float* red = (float*)smem;   // 4 * 4096 f32 = 64 KB
    const int col = lane & 15, rbase = (lane >> 4) * 4;
#pragma unroll
    for (int i = 0; i < 4; i++)
#pragma unroll
        for (int j = 0; j < 4; j++)
#pragma unroll
            for (int r = 0; r < 4; r++) {
                const int dd = i * 16 + rbase + r;
                const int ee = j * 16 + col;
                red[wave * 4096 + dd * 64 + ee] = acc[i][j][r];
            }
    __syncthreads();
    float* cp = ctxp + ((size_t)chunk * 64 + bh) * 4096;
#pragma unroll
    for (int gg = 0; gg < 4; gg++) {
        const int idx = t * 16 + gg * 4;
        f32x4 s = *(const f32x4*)&red[idx];
        s += *(const f32x4*)&red[4096 + idx];
        s += *(const f32x4*)&red[8192 + idx];
        s += *(const f32x4*)&red[12288 + idx];
        *(f32x4*)&cp[idx] = s;
    }
}

// ---------------------------------------------------------------------------
// reduce ctx partials over chunks, apply 1/s_d, transpose [d][e]->[e][d],
// emit bf16 ctxT[bh][e][d]. grid 256.
// ---------------------------------------------------------------------------
__global__ __launch_bounds__(256) void ctx_reduce(const float* __restrict__ ctxp,
                                                  const float2* __restrict__ stats,
                                                  __bf16* __restrict__ ctxT) {
    const int bh = blockIdx.x >> 2, quarter = blockIdx.x & 3;
    const int t = threadIdx.x;
    const int flat = quarter * 1024 + t * 4;   // d-major: d = flat>>6, e0 = flat&63
    const int d = flat >> 6, e0 = flat & 63;
    f32x4 s = (f32x4)(0.0f);
    for (int ch = 0; ch < NCH; ch++)
        s += *(const f32x4*)&ctxp[((size_t)ch * 64 + bh) * 4096 + flat];
    const float inv = stats[bh * 64 + d].y;
    __bf16* o = ctxT + (size_t)bh * 4096;
#pragma unroll
    for (int j = 0; j < 4; j++) o[(e0 + j) * 64 + d] = (__bf16)(s[j] * inv);
}

// ---------------------------------------------------------------------------
// pv_fused: per (bh, 256-col tile): q-softmax (unnormalized exp in LDS bf16)
// + MFMA 256x64 K=64 against ctxT, normalize in epilogue, write bf16 outT.
// ---------------------------------------------------------------------------
#define SPS 66   // LDS row stride (bf16)
__global__ __launch_bounds__(256) void pv_fused(__bf16* __restrict__ qkv,
                                                const __bf16* __restrict__ ctxT) {
    __shared__ __align__(16) __bf16 sp[256 * SPS];   // p rows [n][d]
    __shared__ __align__(16) __bf16 sctx[64 * SPS];  // ctxT rows [e][d]
    __shared__ float sinv[256];
    const int tileN = blockIdx.x;
    const int bh = blockIdx.y;
    const int b = bh >> 3, h = bh & 7;
    const int t = threadIdx.x;
    const int n0 = tileN * 256;
    const __bf16* qbase = qkv + (size_t)b * 1536 * L + (size_t)(h * 64) * L;

    {   // stage ctxT (64x64 bf16)
        const int e = t >> 2, c = t & 3;
        const bf16x8* src = (const bf16x8*)(ctxT + ((size_t)bh * 64 + e) * 64 + c * 16);
        *(bf16x8*)&sctx[e * SPS + c * 16] = src[0];
        *(bf16x8*)&sctx[e * SPS + c * 16 + 8] = src[1];
    }

    // read bf16 q column (coalesced across lanes), exp, sum, stage
    float m = -1e30f;
    float qv[64];
#pragma unroll
    for (int d = 0; d < 64; d++) {
        qv[d] = (float)qbase[(size_t)d * L + n0 + t];
        m = fmaxf(m, qv[d]);
    }
    float s = 0.f;
#pragma unroll
    for (int d0 = 0; d0 < 64; d0 += 8) {
        bf16x8 ek;
#pragma unroll
        for (int j = 0; j < 8; j++) {
            float e = __expf(qv[d0 + j] - m);
            s += e;
            ek[j] = (__bf16)e;
        }
        *(bf16x8*)&sp[t * SPS + d0] = ek;
    }
    sinv[t] = 1.0f / s;
    __syncthreads();

    // MFMA: out[n][e] = sum_d p[n][d] * ctxT[e][d]; 4 waves x 64 rows
    const int wave = t >> 6, lane = t & 63;
    const int wm = wave * 64;
    const int fr = lane & 15, kq = (lane >> 4) * 8;
    f32x4 acc[4][4];
#pragma unroll
    for (int i = 0; i < 4; i++)
#pragma unroll
        for (int j = 0; j < 4; j++) acc[i][j] = (f32x4)(0.0f);
#pragma unroll
    for (int kh = 0; kh < 2; kh++) {
        bf16x8 af[4], bfr[4];
#pragma unroll
        for (int i = 0; i < 4; i++)
            af[i] = *(const bf16x8*)&sp[(wm + i * 16 + fr) * SPS + kh * 32 + kq];
#pragma unroll
        for (int j = 0; j < 4; j++)
            bfr[j] = *(const bf16x8*)&sctx[(j * 16 + fr) * SPS + kh * 32 + kq];
#pragma unroll
        for (int i = 0; i < 4; i++)
#pragma unroll
            for (int j = 0; j < 4; j++)
                acc[i][j] = __builtin_amdgcn_mfma_f32_16x16x32_bf16(af[i], bfr[j], acc[i][j], 0, 0, 0);
    }

    // epilogue: normalize by 1/s[n], write bf16 outT[b][n][h*64+e]
    __bf16* ob = qkv + (size_t)b * 1536 * L + (size_t)512 * L;
    const int col = lane & 15, rbase = (lane >> 4) * 4;
#pragma unroll
    for (int i = 0; i < 4; i++) {
#pragma unroll
        for (int r = 0; r < 4; r++) {
            const int nl = wm + i * 16 + rbase + r;
            const float inv = sinv[nl];
            const size_t rowoff = (size_t)(n0 + nl) * 512 + h * 64;
#pragma unroll
            for (int j = 0; j < 4; j++)
                ob[rowoff + j * 16 + col] = (__bf16)(acc[i][j][r] * inv);
        }
    }
}

// ---------------------------------------------------------------------------
extern "C" void kernel_launch(void* const* d_in, const int* in_sizes, int n_in,
                              void* d_out, int out_size, void* d_ws, size_t ws_size,
                              hipStream_t stream) {
    const float* x    = (const float*)d_in[0];
    const float* Wqkv = (const float*)d_in[1];
    const float* Wout = (const float*)d_in[2];
    const float* bout = (const float*)d_in[3];
    float* y = (float*)d_out;

    __bf16* qkv   = (__bf16*)d_ws;                               // 8*1536*4096 bf16
    float*  ctxp  = (float*)(qkv + (size_t)8 * 1536 * L);        // NCH*64*4096 f32
    __bf16* xb    = (__bf16*)(ctxp + (size_t)NCH * 64 * 4096);   // 8*4096*512 bf16
    __bf16* Wqb   = xb + (size_t)8 * 4096 * 512;                 // 1536*512 bf16
    __bf16* Wob   = Wqb + (size_t)1536 * 512;                    // 512*512 bf16
    float2* stats = (float2*)(Wob + (size_t)512 * 512);          // 4096 float2
    __bf16* ctxT  = (__bf16*)(stats + 4096);                     // 64*4096 bf16

    const int convBlocks = (NX8 + NW18 + NW28 + 255) / 256;
    convert_all<<<dim3(convBlocks), 256, 0, stream>>>(x, Wqkv, Wout, xb);

    // qkv[b][o][l] = sum_d Wqkv[o][d] * x[b][l][d]   (M=1536, N=4096, K=512), bf16 out
    gemm_bf16_pipe<1536, 4096, 512, __bf16><<<dim3(4096 / 128, 1536 / 256, 8), 256, 0, stream>>>(
        Wqb, 0, xb, (size_t)4096 * 512, qkv, (size_t)1536 * 4096, nullptr);

    kstats<<<dim3(4096), 256, 0, stream>>>(qkv, stats);
    context_mfma<<<dim3(NCH, 64), 256, 0, stream>>>(qkv, stats, ctxp);
    ctx_reduce<<<dim3(256), 256, 0, stream>>>(ctxp, stats, ctxT);
    pv_fused<<<dim3(L / 256, 64), 256, 0, stream>>>(qkv, ctxT);

    // y[b][l][d] = sum_c outT[b][l][c] * Wout[d][c] + bout[d]  (M=4096, N=512, K=512), f32 out
    const __bf16* outT = qkv + (size_t)512 * L;
    gemm_bf16_pipe<4096, 512, 512, float><<<dim3(512 / 128, 4096 / 256, 8), 256, 0, stream>>>(
        outT, (size_t)1536 * L, Wob, 0, y, (size_t)4096 * 512, bout);
}

// Round 10
// 266.251 us; speedup vs baseline: 1.0058x; 1.0019x over previous
//
#include <hip/hip_runtime.h>

#define L 4096
#define D 512
#define NCH 16   // context n-chunks (256 n per chunk)

typedef __bf16 bf16x8 __attribute__((ext_vector_type(8)));
typedef float  f32x4  __attribute__((ext_vector_type(4)));

__device__ __forceinline__ void load_lds16(const void* g, void* l) {
    __builtin_amdgcn_global_load_lds(
        (const __attribute__((address_space(1))) void*)g,
        (__attribute__((address_space(3))) void*)l, 16, 0, 0);
}

__device__ __forceinline__ void barrier_mem() {
    asm volatile("" ::: "memory");
    __builtin_amdgcn_s_barrier();
    asm volatile("" ::: "memory");
}

// ---------------------------------------------------------------------------
// merged f32 -> bf16 conversion for x, Wqkv, Wout (contiguous dst regions)
// ---------------------------------------------------------------------------
#define NX8  (8 * 4096 * 512 / 8)
#define NW18 (1536 * 512 / 8)
#define NW28 (512 * 512 / 8)
__global__ __launch_bounds__(256) void convert_all(const float* __restrict__ x,
                                                   const float* __restrict__ Wq,
                                                   const float* __restrict__ Wo,
                                                   __bf16* __restrict__ dst) {
    int i = blockIdx.x * 256 + threadIdx.x;
    if (i >= NX8 + NW18 + NW28) return;
    const float* s;
    if (i < NX8)             s = x  + (size_t)i * 8;
    else if (i < NX8 + NW18) s = Wq + (size_t)(i - NX8) * 8;
    else                     s = Wo + (size_t)(i - NX8 - NW18) * 8;
    float4 a = ((const float4*)s)[0], b = ((const float4*)s)[1];
    bf16x8 o = {(__bf16)a.x, (__bf16)a.y, (__bf16)a.z, (__bf16)a.w,
                (__bf16)b.x, (__bf16)b.y, (__bf16)b.z, (__bf16)b.w};
    *(bf16x8*)(dst + (size_t)i * 8) = o;
}

// ---------------------------------------------------------------------------
// 256x256-tile TN bf16 MFMA GEMM, 8-PHASE schedule (m201-class, T3+T4+T5).
// C[b][m][n] = sum_k A[b][m][k]*B[b][n][k] (+bias[n]). 512 thr = 8 waves
// (2M x 4N), per-wave 128x64 output, acc[8][4] f32x4 (R9's verified layout).
// LDS: sA[2][256x64] + sB[2][256x64] = 128 KB, double-buffered by K-tile
// parity p = kt&1. K-tile = BK=64 = 2 k-halves of 32.
// Per K-tile: 4 phases, each {ds_read subtile; (stage); barrier; lgkm(0);
//   sched_barrier; setprio(1) 16 MFMA setprio(0); barrier}:
//   ph0: rd B(kh0,4)+A(i0-3,kh0,4)   + stage kt+1 half0 (4 gload_lds)
//   ph1: rd A(i4-7,kh0,4)            + stage kt+1 half1 (4 gload_lds)
//   ph2: rd B(kh1,4)+A(i0-3,kh1,4)
//   ph3: rd A(i4-7,kh1,4)
// vmcnt COUNTED once per K-tile (kt.ph0, after issuing kt+1 half0):
//   outstanding <= kt's 8 (staged @ kt-1 ph0/ph1) + kt+1's 4 -> vmcnt(4)
//   proves kt fully landed, keeps kt+1 half0 in flight. Tail kt=NT-1: vmcnt(0).
// WAR: buf p^1's last reads (K-tile kt-1) drain at each phase's lgkm(0),
//   all before kt-1.ph3's closing barrier; stages into p^1 issue after it.
// RAW: ph0's vmcnt+barrier proves buf p before any ds_read of it.
// Swizzle (128B rows, 8 chunks): slot (row,cc) holds global chunk cc^(row&7);
//   read chunk (kh*4+g)^(fr&7) -> 2-way bank aliasing max (free, m136); R1
//   measured SQ_LDS_BANK_CONFLICT = 0 with this exact scheme.
// ---------------------------------------------------------------------------
template <int M, int N, int K, typename CT>
__global__ __launch_bounds__(512, 2) void gemm_bf16_8ph(
    const __bf16* __restrict__ A, size_t aStride,
    const __bf16* __restrict__ B, size_t bStride,
    CT* __restrict__ C, size_t cStride,
    const float* __restrict__ bias) {
    __shared__ __align__(16) __bf16 sB[2][256 * 64];   // 64 KB
    __shared__ __align__(16) __bf16 sA[2][256 * 64];   // 64 KB
    constexpr int NT = K / 64;                          // 8
    const int b  = blockIdx.z;
    const int m0 = blockIdx.y * 256;
    const int n0 = blockIdx.x * 256;
    const int t    = threadIdx.x;
    const int wave = t >> 6, lane = t & 63;
    const int wm = (wave >> 2) * 128;   // 2 M-halves
    const int wn = (wave & 3) * 64;     // 4 N-quads
    const int fr = lane & 15, g = lane >> 4;
    const __bf16* Ab = A + (size_t)b * aStride + (size_t)m0 * K;
    const __bf16* Bb = B + (size_t)b * bStride + (size_t)n0 * K;
    CT* Cb = C + (size_t)b * cStride;

    // per-thread global source pointers (pre-swizzled chunk), computed once.
    // granule gi = k*512 + t (16B each): row = gi>>3 (0..255), cc = gi&7.
    const __bf16* pA_[4];
    const __bf16* pB_[4];
#pragma unroll
    for (int k = 0; k < 4; ++k) {
        const int gi = k * 512 + t, row = gi >> 3, cc = gi & 7;
        pA_[k] = Ab + (size_t)row * K + (cc ^ (row & 7)) * 8;
        pB_[k] = Bb + (size_t)row * K + (cc ^ (row & 7)) * 8;
    }
    // lane-constant LDS chunk offsets (elements) for kh = 0,1
    const int lc0 = ((0 + g) ^ (fr & 7)) * 8;
    const int lc1 = ((4 + g) ^ (fr & 7)) * 8;

    f32x4 acc[8][4];
#pragma unroll
    for (int i = 0; i < 8; i++)
#pragma unroll
        for (int j = 0; j < 4; j++) acc[i][j] = (f32x4)(0.0f);

    // stage half h of K-tile kt into buf pb: h0 -> rows 0..127 (k=0,1),
    // h1 -> rows 128..255 (k=2,3); A and B interleaved (4 loads).
    auto stageH = [&](int kt, int pb, int h) {
#pragma unroll
        for (int k = h * 2; k < h * 2 + 2; ++k) {
            load_lds16(pA_[k] + kt * 64, &sA[pb][(k * 512 + t) * 8]);
            load_lds16(pB_[k] + kt * 64, &sB[pb][(k * 512 + t) * 8]);
        }
    };

    // prologue: stage K-tile 0 fully (8 loads)
    stageH(0, 0, 0);
    stageH(0, 0, 1);

    bf16x8 fB[4], fA[4];
#pragma unroll
    for (int kt = 0; kt < NT; ++kt) {
        const int p = kt & 1;
        // ---------------- ph0 (K-tile start) ----------------
        if (kt + 1 < NT) {
            stageH(kt + 1, p ^ 1, 0);
            asm volatile("s_waitcnt vmcnt(4)" ::: "memory");
        } else {
            asm volatile("s_waitcnt vmcnt(0)" ::: "memory");
        }
        barrier_mem();                       // buf p fully staged (all waves)
#pragma unroll
        for (int j = 0; j < 4; ++j)
            fB[j] = *(const bf16x8*)&sB[p][(wn + j * 16 + fr) * 64 + lc0];
#pragma unroll
        for (int i = 0; i < 4; ++i)
            fA[i] = *(const bf16x8*)&sA[p][(wm + i * 16 + fr) * 64 + lc0];
        asm volatile("s_waitcnt lgkmcnt(0)" ::: "memory");
        __builtin_amdgcn_sched_barrier(0);
        __builtin_amdgcn_s_setprio(1);
#pragma unroll
        for (int i = 0; i < 4; ++i)
#pragma unroll
            for (int j = 0; j < 4; ++j)
                acc[i][j] = __builtin_amdgcn_mfma_f32_16x16x32_bf16(fA[i], fB[j], acc[i][j], 0, 0, 0);
        __builtin_amdgcn_s_setprio(0);
        barrier_mem();
        // ---------------- ph1 ----------------
#pragma unroll
        for (int i = 0; i < 4; ++i)
            fA[i] = *(const bf16x8*)&sA[p][(wm + 64 + i * 16 + fr) * 64 + lc0];
        if (kt + 1 < NT) stageH(kt + 1, p ^ 1, 1);
        barrier_mem();
        asm volatile("s_waitcnt lgkmcnt(0)" ::: "memory");
        __builtin_amdgcn_sched_barrier(0);
        __builtin_amdgcn_s_setprio(1);
#pragma unroll
        for (int i = 0; i < 4; ++i)
#pragma unroll
            for (int j = 0; j < 4; ++j)
                acc[4 + i][j] = __builtin_amdgcn_mfma_f32_16x16x32_bf16(fA[i], fB[j], acc[4 + i][j], 0, 0, 0);
        __builtin_amdgcn_s_setprio(0);
        barrier_mem();
        // ---------------- ph2 ----------------
#pragma unroll
        for (int j = 0; j < 4; ++j)
            fB[j] = *(const bf16x8*)&sB[p][(wn + j * 16 + fr) * 64 + lc1];
#pragma unroll
        for (int i = 0; i < 4; ++i)
            fA[i] = *(const bf16x8*)&sA[p][(wm + i * 16 + fr) * 64 + lc1];
        barrier_mem();
        asm volatile("s_waitcnt lgkmcnt(0)" ::: "memory");
        __builtin_amdgcn_sched_barrier(0);
        __builtin_amdgcn_s_setprio(1);
#pragma unroll
        for (int i = 0; i < 4; ++i)
#pragma unroll
            for (int j = 0; j < 4; ++j)
                acc[i][j] = __builtin_amdgcn_mfma_f32_16x16x32_bf16(fA[i], fB[j], acc[i][j], 0, 0, 0);
        __builtin_amdgcn_s_setprio(0);
        barrier_mem();
        // ---------------- ph3 ----------------
#pragma unroll
        for (int i = 0; i < 4; ++i)
            fA[i] = *(const bf16x8*)&sA[p][(wm + 64 + i * 16 + fr) * 64 + lc1];
        barrier_mem();
        asm volatile("s_waitcnt lgkmcnt(0)" ::: "memory");
        __builtin_amdgcn_sched_barrier(0);
        __builtin_amdgcn_s_setprio(1);
#pragma unroll
        for (int i = 0; i < 4; ++i)
#pragma unroll
            for (int j = 0; j < 4; ++j)
                acc[4 + i][j] = __builtin_amdgcn_mfma_f32_16x16x32_bf16(fA[i], fB[j], acc[4 + i][j], 0, 0, 0);
        __builtin_amdgcn_s_setprio(0);
        barrier_mem();
    }

    // epilogue: j-innermost so adjacent 32B chunks issue back-to-back
    const int rb = g * 4;
    float bv[4];
#pragma unroll
    for (int j = 0; j < 4; ++j) bv[j] = bias ? bias[n0 + wn + j * 16 + fr] : 0.0f;
#pragma unroll
    for (int i = 0; i < 8; ++i) {
#pragma unroll
        for (int r = 0; r < 4; ++r) {
            const int m = m0 + wm + i * 16 + rb + r;
            CT* rowp = Cb + (size_t)m * N + n0 + wn + fr;
#pragma unroll
            for (int j = 0; j < 4; ++j)
                rowp[j * 16] = (CT)(acc[i][j][r] + bv[j]);
        }
    }
}

// ---------------------------------------------------------------------------
// k-row stats over bf16 k rows: per row compute (max, 1/sumexp). grid 4096.
// ---------------------------------------------------------------------------
__global__ __launch_bounds__(256) void kstats(const __bf16* __restrict__ qkv,
                                              float2* __restrict__ stats) {
    const int r = blockIdx.x;
    const int b = r >> 9, hc = r & 511;
    const __bf16* row = qkv + (size_t)b * 1536 * L + (size_t)(512 + hc) * L;
    __shared__ float sred[4];
    const int t = threadIdx.x;
    const bf16x8* p = (const bf16x8*)row;
    bf16x8 c0 = p[t * 2], c1 = p[t * 2 + 1];
    float v[16];
    float m = -1e30f;
#pragma unroll
    for (int j = 0; j < 8; j++) {
        v[j] = (float)c0[j];
        v[8 + j] = (float)c1[j];
    }
#pragma unroll
    for (int j = 0; j < 16; j++) m = fmaxf(m, v[j]);
#pragma unroll
    for (int off = 32; off > 0; off >>= 1) m = fmaxf(m, __shfl_down(m, off, 64));
    if ((t & 63) == 0) sred[t >> 6] = m;
    __syncthreads();
    const float m4 = fmaxf(fmaxf(sred[0], sred[1]), fmaxf(sred[2], sred[3]));
    float s = 0.f;
#pragma unroll
    for (int j = 0; j < 16; j++) s += __expf(v[j] - m4);
#pragma unroll
    for (int off = 32; off > 0; off >>= 1) s += __shfl_down(s, off, 64);
    __syncthreads();
    if ((t & 63) == 0) sred[t >> 6] = s;
    __syncthreads();
    if (t == 0) {
        const float stot = sred[0] + sred[1] + sred[2] + sred[3];
        stats[r] = make_float2(m4, 1.0f / stot);
    }
}

// ---------------------------------------------------------------------------
// MFMA context partials: ctxp[chunk][bh][d][e] (f32, d-major) =
//   sum_{n in chunk} exp(k[d,n]-m_d) * v[e,n]   (un-normalized; 1/s at reduce)
// grid (NCH, 64 bh), block 256. Each of 4 waves takes a 64-n K-slice.
// ---------------------------------------------------------------------------
#define SKS 264   // LDS bf16 row stride (256 data + 8 pad)
__global__ __launch_bounds__(256) void context_mfma(const __bf16* __restrict__ qkv,
                                                    const float2* __restrict__ stats,
                                                    float* __restrict__ ctxp) {
    __shared__ __align__(16) __bf16 smem[2 * 64 * SKS];  // 67.6 KB; reused as f32 red[4][4096]
    __shared__ float smax[64];
    __bf16* sk = smem;
    __bf16* sv = smem + 64 * SKS;
    const int chunk = blockIdx.x;
    const int bh = blockIdx.y;
    const int b = bh >> 3, h = bh & 7;
    const __bf16* kbase = qkv + (size_t)b * 1536 * L + (size_t)(512 + h * 64) * L;
    const __bf16* vbase = qkv + (size_t)b * 1536 * L + (size_t)(1024 + h * 64) * L;
    const int t = threadIdx.x;
    if (t < 64) smax[t] = stats[bh * 64 + t].x;
    __syncthreads();

    // stage: thread t -> row d = t>>2, n-quarter (t&3)*64
    {
        const int d = t >> 2, noff = (t & 3) * 64;
        const int n0 = chunk * 256;
        const __bf16* kp = kbase + (size_t)d * L + n0 + noff;
        const __bf16* vp = vbase + (size_t)d * L + n0 + noff;
        const float md = smax[d];
#pragma unroll
        for (int c = 0; c < 8; c++) {
            bf16x8 kk = *(const bf16x8*)(kp + c * 8);
            bf16x8 vv = *(const bf16x8*)(vp + c * 8);
            bf16x8 ek;
#pragma unroll
            for (int j = 0; j < 8; j++) ek[j] = (__bf16)__expf((float)kk[j] - md);
            *(bf16x8*)&sk[d * SKS + noff + c * 8] = ek;
            *(bf16x8*)&sv[d * SKS + noff + c * 8] = vv;
        }
    }
    __syncthreads();

    // MFMA: wave w covers n in [w*64, w*64+64)
    const int wave = t >> 6, lane = t & 63;
    const int fr = lane & 15, kq = (lane >> 4) * 8;
    f32x4 acc[4][4];
#pragma unroll
    for (int i = 0; i < 4; i++)
#pragma unroll
        for (int j = 0; j < 4; j++) acc[i][j] = (f32x4)(0.0f);
#pragma unroll
    for (int kh = 0; kh < 2; kh++) {
        const int koff = wave * 64 + kh * 32 + kq;
        bf16x8 af[4], bfr[4];
#pragma unroll
        for (int i = 0; i < 4; i++) {
            af[i]  = *(const bf16x8*)&sk[(i * 16 + fr) * SKS + koff];
            bfr[i] = *(const bf16x8*)&sv[(i * 16 + fr) * SKS + koff];
        }
#pragma unroll
        for (int i = 0; i < 4; i++)
#pragma unroll
            for (int j = 0; j < 4; j++)
                acc[i][j] = __builtin_amdgcn_mfma_f32_16x16x32_bf16(af[i], bfr[j], acc[i][j], 0, 0, 0);
    }
    __syncthreads();   // MFMA LDS reads done; safe to overwrite smem

    // cross-wave reduce via LDS: red[w][d*64+e] (d = A rows, e = B rows)
    float* red = (float*)smem;   // 4 * 4096 f32 = 64 KB
    const int col = lane & 15, rbase = (lane >> 4) * 4;
#pragma unroll
    for (int i = 0; i < 4; i++)
#pragma unroll
        for (int j = 0; j < 4; j++)
#pragma unroll
            for (int r = 0; r < 4; r++) {
                const int dd = i * 16 + rbase + r;
                const int ee = j * 16 + col;
                red[wave * 4096 + dd * 64 + ee] = acc[i][j][r];
            }
    __syncthreads();
    float* cp = ctxp + ((size_t)chunk * 64 + bh) * 4096;
#pragma unroll
    for (int gg = 0; gg < 4; gg++) {
        const int idx = t * 16 + gg * 4;
        f32x4 s = *(const f32x4*)&red[idx];
        s += *(const f32x4*)&red[4096 + idx];
        s += *(const f32x4*)&red[8192 + idx];
        s += *(const f32x4*)&red[12288 + idx];
        *(f32x4*)&cp[idx] = s;
    }
}

// ---------------------------------------------------------------------------
// reduce ctx partials over chunks, apply 1/s_d, transpose [d][e]->[e][d],
// emit bf16 ctxT[bh][e][d]. grid 256.
// ---------------------------------------------------------------------------
__global__ __launch_bounds__(256) void ctx_reduce(const float* __restrict__ ctxp,
                                                  const float2* __restrict__ stats,
                                                  __bf16* __restrict__ ctxT) {
    const int bh = blockIdx.x >> 2, quarter = blockIdx.x & 3;
    const int t = threadIdx.x;
    const int flat = quarter * 1024 + t * 4;   // d-major: d = flat>>6, e0 = flat&63
    const int d = flat >> 6, e0 = flat & 63;
    f32x4 s = (f32x4)(0.0f);
    for (int ch = 0; ch < NCH; ch++)
        s += *(const f32x4*)&ctxp[((size_t)ch * 64 + bh) * 4096 + flat];
    const float inv = stats[bh * 64 + d].y;
    __bf16* o = ctxT + (size_t)bh * 4096;
#pragma unroll
    for (int j = 0; j < 4; j++) o[(e0 + j) * 64 + d] = (__bf16)(s[j] * inv);
}

// ---------------------------------------------------------------------------
// pv_fused: per (bh, 256-col tile): q-softmax (unnormalized exp in LDS bf16)
// + MFMA 256x64 K=64 against ctxT, normalize in epilogue, write bf16 outT.
// ---------------------------------------------------------------------------
#define SPS 66   // LDS row stride (bf16)
__global__ __launch_bounds__(256) void pv_fused(__bf16* __restrict__ qkv,
                                                const __bf16* __restrict__ ctxT) {
    __shared__ __align__(16) __bf16 sp[256 * SPS];   // p rows [n][d]
    __shared__ __align__(16) __bf16 sctx[64 * SPS];  // ctxT rows [e][d]
    __shared__ float sinv[256];
    const int tileN = blockIdx.x;
    const int bh = blockIdx.y;
    const int b = bh >> 3, h = bh & 7;
    const int t = threadIdx.x;
    const int n0 = tileN * 256;
    const __bf16* qbase = qkv + (size_t)b * 1536 * L + (size_t)(h * 64) * L;

    {   // stage ctxT (64x64 bf16)
        const int e = t >> 2, c = t & 3;
        const bf16x8* src = (const bf16x8*)(ctxT + ((size_t)bh * 64 + e) * 64 + c * 16);
        *(bf16x8*)&sctx[e * SPS + c * 16] = src[0];
        *(bf16x8*)&sctx[e * SPS + c * 16 + 8] = src[1];
    }

    // read bf16 q column (coalesced across lanes), exp, sum, stage
    float m = -1e30f;
    float qv[64];
#pragma unroll
    for (int d = 0; d < 64; d++) {
        qv[d] = (float)qbase[(size_t)d * L + n0 + t];
        m = fmaxf(m, qv[d]);
    }
    float s = 0.f;
#pragma unroll
    for (int d0 = 0; d0 < 64; d0 += 8) {
        bf16x8 ek;
#pragma unroll
        for (int j = 0; j < 8; j++) {
            float e = __expf(qv[d0 + j] - m);
            s += e;
            ek[j] = (__bf16)e;
        }
        *(bf16x8*)&sp[t * SPS + d0] = ek;
    }
    sinv[t] = 1.0f / s;
    __syncthreads();

    // MFMA: out[n][e] = sum_d p[n][d] * ctxT[e][d]; 4 waves x 64 rows
    const int wave = t >> 6, lane = t & 63;
    const int wm = wave * 64;
    const int fr = lane & 15, kq = (lane >> 4) * 8;
    f32x4 acc[4][4];
#pragma unroll
    for (int i = 0; i < 4; i++)
#pragma unroll
        for (int j = 0; j < 4; j++) acc[i][j] = (f32x4)(0.0f);
#pragma unroll
    for (int kh = 0; kh < 2; kh++) {
        bf16x8 af[4], bfr[4];
#pragma unroll
        for (int i = 0; i < 4; i++)
            af[i] = *(const bf16x8*)&sp[(wm + i * 16 + fr) * SPS + kh * 32 + kq];
#pragma unroll
        for (int j = 0; j < 4; j++)
            bfr[j] = *(const bf16x8*)&sctx[(j * 16 + fr) * SPS + kh * 32 + kq];
#pragma unroll
        for (int i = 0; i < 4; i++)
#pragma unroll
            for (int j = 0; j < 4; j++)
                acc[i][j] = __builtin_amdgcn_mfma_f32_16x16x32_bf16(af[i], bfr[j], acc[i][j], 0, 0, 0);
    }

    // epilogue: normalize by 1/s[n], write bf16 outT[b][n][h*64+e]
    __bf16* ob = qkv + (size_t)b * 1536 * L + (size_t)512 * L;
    const int col = lane & 15, rbase = (lane >> 4) * 4;
#pragma unroll
    for (int i = 0; i < 4; i++) {
#pragma unroll
        for (int r = 0; r < 4; r++) {
            const int nl = wm + i * 16 + rbase + r;
            const float inv = sinv[nl];
            const size_t rowoff = (size_t)(n0 + nl) * 512 + h * 64;
#pragma unroll
            for (int j = 0; j < 4; j++)
                ob[rowoff + j * 16 + col] = (__bf16)(acc[i][j][r] * inv);
        }
    }
}

// ---------------------------------------------------------------------------
extern "C" void kernel_launch(void* const* d_in, const int* in_sizes, int n_in,
                              void* d_out, int out_size, void* d_ws, size_t ws_size,
                              hipStream_t stream) {
    const float* x    = (const float*)d_in[0];
    const float* Wqkv = (const float*)d_in[1];
    const float* Wout = (const float*)d_in[2];
    const float* bout = (const float*)d_in[3];
    float* y = (float*)d_out;

    __bf16* qkv   = (__bf16*)d_ws;                               // 8*1536*4096 bf16
    float*  ctxp  = (float*)(qkv + (size_t)8 * 1536 * L);        // NCH*64*4096 f32
    __bf16* xb    = (__bf16*)(ctxp + (size_t)NCH * 64 * 4096);   // 8*4096*512 bf16
    __bf16* Wqb   = xb + (size_t)8 * 4096 * 512;                 // 1536*512 bf16
    __bf16* Wob   = Wqb + (size_t)1536 * 512;                    // 512*512 bf16
    float2* stats = (float2*)(Wob + (size_t)512 * 512);          // 4096 float2
    __bf16* ctxT  = (__bf16*)(stats + 4096);                     // 64*4096 bf16

    const int convBlocks = (NX8 + NW18 + NW28 + 255) / 256;
    convert_all<<<dim3(convBlocks), 256, 0, stream>>>(x, Wqkv, Wout, xb);

    // qkv[b][o][l] = sum_d Wqkv[o][d] * x[b][l][d]   (M=1536, N=4096, K=512), bf16 out
    gemm_bf16_8ph<1536, 4096, 512, __bf16><<<dim3(4096 / 256, 1536 / 256, 8), 512, 0, stream>>>(
        Wqb, 0, xb, (size_t)4096 * 512, qkv, (size_t)1536 * 4096, nullptr);

    kstats<<<dim3(4096), 256, 0, stream>>>(qkv, stats);
    context_mfma<<<dim3(NCH, 64), 256, 0, stream>>>(qkv, stats, ctxp);
    ctx_reduce<<<dim3(256), 256, 0, stream>>>(ctxp, stats, ctxT);
    pv_fused<<<dim3(L / 256, 64), 256, 0, stream>>>(qkv, ctxT);

    // y[b][l][d] = sum_c outT[b][l][c] * Wout[d][c] + bout[d]  (M=4096, N=512, K=512), f32 out
    const __bf16* outT = qkv + (size_t)512 * L;
    gemm_bf16_8ph<4096, 512, 512, float><<<dim3(512 / 256, 4096 / 256, 8), 512, 0, stream>>>(
        outT, (size_t)1536 * L, Wob, 0, y, (size_t)4096 * 512, bout);
}